// Round 12
// baseline (118.339 us; speedup 1.0000x reference)
//
#include <hip/hip_runtime.h>
#include <hip/hip_bf16.h>
#include <math.h>

// EulerCausalAttention on MI355X (gfx950).
// prep (Q/K euler features, log2e folded into Q) ; wconv ; V-GEMM -> Vt[b,h,d,s] ;
// causal flash attention (2-wave blocks x 64 q-rows/wave: halves LDS traffic
// vs 4x32; KVBLK=64, balanced qt pairing, counted-vmcnt dbuf, setprio) ;
// out-GEMM. GEMMs: 64x128 tiles (512 blocks = 2/CU) + counted-vmcnt pipeline.

typedef __attribute__((ext_vector_type(8))) __bf16 bf16x8;
typedef __attribute__((ext_vector_type(4))) __bf16 bf16x4;
typedef __attribute__((ext_vector_type(4))) float f32x4;
typedef unsigned short ushort_t;
typedef unsigned int uint_t;

#define LUTC 651.8986469044033f       // 4096 / (2*pi)
#define ANG 0.0015339807878856412f    // 2*pi / 4096
#define QSCL 0.12751743590489435f     // log2(e) / sqrt(128)  (folded into Q)

__device__ __forceinline__ float fast_exp2(float x) {
#if __has_builtin(__builtin_amdgcn_exp2f)
  return __builtin_amdgcn_exp2f(x);
#else
  return exp2f(x);
#endif
}

__device__ __forceinline__ ushort_t f2bf(float f) {
  union { __bf16 b; ushort_t u; } cv;
  cv.b = (__bf16)f;
  return cv.u;
}

__device__ __forceinline__ void store8(ushort_t* p, const ushort_t v[8]) {
  uint4 u;
  u.x = (uint_t)v[0] | ((uint_t)v[1] << 16);
  u.y = (uint_t)v[2] | ((uint_t)v[3] << 16);
  u.z = (uint_t)v[4] | ((uint_t)v[5] << 16);
  u.w = (uint_t)v[6] | ((uint_t)v[7] << 16);
  *(uint4*)p = u;
}

__device__ __forceinline__ void gl_lds16(const void* g, void* l) {
  __builtin_amdgcn_global_load_lds(
      (__attribute__((address_space(1))) void*)(g),
      (__attribute__((address_space(3))) void*)(l),
      16, 0, 0);
}

// ---------------------------------------------------------------- prep ------
__global__ __launch_bounds__(256) void prep_kernel(
    const float* __restrict__ x, const float* __restrict__ wq, const float* __restrict__ bq,
    const float* __restrict__ wk, const float* __restrict__ bk,
    ushort_t* __restrict__ Qs, ushort_t* __restrict__ Ks, ushort_t* __restrict__ xb)
{
  int t = blockIdx.x * 256 + threadIdx.x;   // 131072 threads
  int dm8 = t & 127;
  int g = t >> 7;                            // token group of 4
  int dm0 = dm8 * 8;
  int h = dm0 >> 6;

  float aq[8], cq[8], ak[8], ck[8];
#pragma unroll
  for (int j = 0; j < 8; ++j) {
    aq[j] = LUTC / (1.0f + fabsf(wq[dm0 + j]));
    cq[j] = LUTC * bq[dm0 + j];
    ak[j] = LUTC / (1.0f + fabsf(wk[dm0 + j]));
    ck[j] = LUTC * bk[dm0 + j];
  }
  for (int i = 0; i < 4; ++i) {
    int bs = g * 4 + i;
    int b = bs >> 11, s = bs & 2047;
    const float4* xp4 = (const float4*)(x + (size_t)bs * 1024 + dm0);
    float4 xa = xp4[0], xbv4 = xp4[1];
    float xv[8] = {xa.x, xa.y, xa.z, xa.w, xbv4.x, xbv4.y, xbv4.z, xbv4.w};
    ushort_t qc[8], qs[8], kc[8], ks[8], xo[8];
#pragma unroll
    for (int j = 0; j < 8; ++j) {
      int iq = ((int)rintf(fmaf(xv[j], aq[j], cq[j]))) & 4095;
      float sq, cqv;
      __sincosf((float)iq * ANG, &sq, &cqv);
      int ik = ((int)rintf(fmaf(xv[j], ak[j], ck[j]))) & 4095;
      float sk, ckv;
      __sincosf((float)ik * ANG, &sk, &ckv);
      qc[j] = f2bf(cqv * QSCL);
      qs[j] = f2bf(sq * QSCL);
      kc[j] = f2bf(ckv);
      ks[j] = f2bf(sk);
      xo[j] = f2bf(xv[j]);
    }
    size_t qb = ((size_t)(b * 16 + h) * 2048 + s) * 128 + (dm0 & 63);
    store8(Qs + qb, qc);        store8(Qs + qb + 64, qs);
    store8(Ks + qb, kc);        store8(Ks + qb + 64, ks);
    store8(xb + (size_t)bs * 1024 + dm0, xo);
  }
}

// ---------------------------------------------------------------- wconv -----
__global__ __launch_bounds__(256) void wconv_kernel(
    const float* __restrict__ vw, const float* __restrict__ ow,
    ushort_t* __restrict__ vwb, ushort_t* __restrict__ owb)
{
  int t = blockIdx.x * 256 + threadIdx.x;   // 262144 threads
  const float* src;
  ushort_t* dst;
  int i;
  if (t < 131072) { src = vw; dst = vwb; i = t; }
  else            { src = ow; dst = owb; i = t - 131072; }
  const float4* p4 = (const float4*)(src + (size_t)i * 8);
  float4 a = p4[0], b = p4[1];
  float v[8] = {a.x, a.y, a.z, a.w, b.x, b.y, b.z, b.w};
  ushort_t o[8];
#pragma unroll
  for (int j = 0; j < 8; ++j) o[j] = f2bf(v[j]);
  store8(dst + (size_t)i * 8, o);
}

// ---------------------------------------------------------------- GEMM ------
// Tile 64(m) x 128(n), 4 waves, K-step 64, 512 blocks = 2/CU, counted-vmcnt.
template <int EPI>
__global__ __launch_bounds__(256) void gemm_nt(
    const ushort_t* __restrict__ A, const ushort_t* __restrict__ B,
    float* __restrict__ Cf, ushort_t* __restrict__ Cb, int M, int N, int K)
{
  __shared__ __align__(16) ushort_t As[2][64 * 64];    // 2 x 8KB
  __shared__ __align__(16) ushort_t Bs[2][128 * 64];   // 2 x 16KB
  const int l = threadIdx.x & 63;
  const int w = threadIdx.x >> 6;
  const int g = l >> 4, lo = l & 15;
  const int mt = blockIdx.x % (M >> 6);
  const int nt = blockIdx.x / (M >> 6);
  const int m0 = mt << 6, n0 = nt << 7;

  const f32x4 zero4 = {0.f, 0.f, 0.f, 0.f};
  f32x4 acc[4][2];
#pragma unroll
  for (int i = 0; i < 4; ++i)
#pragma unroll
    for (int j = 0; j < 2; ++j) acc[i][j] = zero4;

  const int nk = K >> 6;   // 16 for K=1024

#define GEMM_STAGE(buf, k0_)                                                    \
  {                                                                             \
    int k0__ = (k0_);                                                           \
    _Pragma("unroll")                                                           \
    for (int i = 0; i < 2; ++i) {                                               \
      int ci = (w * 2 + i) * 64 + l;                                            \
      int r = ci >> 3, c = (ci & 7) ^ (r & 7);                                  \
      gl_lds16(A + (size_t)(m0 + r) * K + k0__ + c * 8, &As[buf][(w * 2 + i) * 512]); \
    }                                                                           \
    _Pragma("unroll")                                                           \
    for (int i = 0; i < 4; ++i) {                                               \
      int ci = (w * 4 + i) * 64 + l;                                            \
      int r = ci >> 3, c = (ci & 7) ^ (r & 7);                                  \
      gl_lds16(B + (size_t)(n0 + r) * K + k0__ + c * 8, &Bs[buf][(w * 4 + i) * 512]); \
    }                                                                           \
  }

  GEMM_STAGE(0, 0);
  GEMM_STAGE(1, 64);
  asm volatile("s_waitcnt vmcnt(6)" ::: "memory");   // tile 0 landed
  __builtin_amdgcn_s_barrier();
  __builtin_amdgcn_sched_barrier(0);

  for (int t = 0; t < nk; ++t) {
    int cb = t & 1;
#pragma unroll
    for (int kk = 0; kk < 2; ++kk) {
      bf16x8 af[4], bfr[2];
#pragma unroll
      for (int mi = 0; mi < 4; ++mi) {
        int r = mi * 16 + lo;
        int ch = (g + 4 * kk) ^ (r & 7);
        af[mi] = *(const bf16x8*)&As[cb][r * 64 + ch * 8];
      }
#pragma unroll
      for (int ni = 0; ni < 2; ++ni) {
        int r = w * 32 + ni * 16 + lo;
        int ch = (g + 4 * kk) ^ (r & 7);
        bfr[ni] = *(const bf16x8*)&Bs[cb][r * 64 + ch * 8];
      }
#pragma unroll
      for (int mi = 0; mi < 4; ++mi)
#pragma unroll
        for (int ni = 0; ni < 2; ++ni)
          acc[mi][ni] = __builtin_amdgcn_mfma_f32_16x16x32_bf16(af[mi], bfr[ni], acc[mi][ni], 0, 0, 0);
    }
    __builtin_amdgcn_sched_barrier(0);
    asm volatile("s_waitcnt lgkmcnt(0)" ::: "memory");
    __builtin_amdgcn_s_barrier();                    // all waves done reading cb
    if (t + 2 < nk) {
      GEMM_STAGE(cb, (t + 2) * 64);
      asm volatile("s_waitcnt vmcnt(6)" ::: "memory");  // tile t+1 landed
    } else {
      asm volatile("s_waitcnt vmcnt(0)" ::: "memory");
    }
    __builtin_amdgcn_s_barrier();
    __builtin_amdgcn_sched_barrier(0);
  }
#undef GEMM_STAGE

#pragma unroll
  for (int mi = 0; mi < 4; ++mi)
#pragma unroll
    for (int ni = 0; ni < 2; ++ni)
#pragma unroll
      for (int reg = 0; reg < 4; ++reg) {
        int row = m0 + mi * 16 + g * 4 + reg;
        int col = n0 + w * 32 + ni * 16 + lo;
        float v = acc[mi][ni][reg];
        if (EPI == 0) {
          Cf[(size_t)row * N + col] = v;
        } else {
          size_t o = (size_t)(col >> 11) * (1024 * 2048) + (size_t)row * 2048 + (col & 2047);
          Cb[o] = f2bf(v);
        }
      }
}

// ------------------------------------------------------------- attention ----
// 512 blocks x 128 threads (2 waves x 64 q-rows each, QBLK=128, KVBLK=64,
// 48KB LDS). qm=4: each wave's 16 K-frag reads feed 4x the MFMAs of the old
// 4x32 layout -> LDS traffic halves (the pipe that dominated per-step time).
// Balanced mapping (round-10): ids 0..255 -> qt=15-(id>>5), ids 256..511 ->
// qt=(id-256)>>5. Counted-vmcnt depth-2 loop (12 loads/stage -> vmcnt(12)).

template<bool MASKED>
__device__ __forceinline__ void attn_tile(
    const ushort_t* __restrict__ Kc, const ushort_t* __restrict__ Vc,
    const bf16x8 (&qf)[4][4], f32x4 (&accO)[4][4], f32x4 (&acc_l)[4],
    int kb, int qw, int lo, int g, const bf16x8& ones)
{
  const f32x4 zero4 = {0.f, 0.f, 0.f, 0.f};
  bf16x8 pa[4][2];
#pragma unroll
  for (int ns = 0; ns < 4; ++ns) {
    f32x4 sc[4];
#pragma unroll
    for (int qm = 0; qm < 4; ++qm) sc[qm] = zero4;
#pragma unroll
    for (int e = 0; e < 4; ++e) {
      int kr = ns * 16 + lo;
      int cc = (g + 4 * e) ^ (kr & 7);
      bf16x8 kf = *(const bf16x8*)&Kc[kr * 128 + cc * 8];
#pragma unroll
      for (int qm = 0; qm < 4; ++qm)
        sc[qm] = __builtin_amdgcn_mfma_f32_16x16x32_bf16(kf, qf[qm][e], sc[qm], 0, 0, 0);
    }
#pragma unroll
    for (int qm = 0; qm < 4; ++qm) {
#pragma unroll
      for (int reg = 0; reg < 4; ++reg) {
        float sv = sc[qm][reg];
        if (MASKED) {
          int ka = kb + ns * 16 + g * 4 + reg;
          int qa = qw + qm * 16 + lo;
          sv = (ka <= qa) ? sv : -__builtin_inff();
        }
        pa[qm][ns >> 1][(ns & 1) * 4 + reg] = (__bf16)fast_exp2(sv);
      }
    }
  }

  // O += P V ; rowsum += P * ones  (V-frag reads shared across the 4 qm)
#pragma unroll
  for (int kk = 0; kk < 2; ++kk) {
#pragma unroll
    for (int nd = 0; nd < 4; ++nd) {
      int vr = nd * 16 + lo;
      int h8 = (g & 1) * 4;
      int cc0 = (4 * kk + (g >> 1)) ^ (vr & 7);
      int cc1 = (4 * kk + 2 + (g >> 1)) ^ (vr & 7);
      union { bf16x8 v8; bf16x4 v4[2]; } u;
      u.v4[0] = *(const bf16x4*)&Vc[vr * 64 + cc0 * 8 + h8];
      u.v4[1] = *(const bf16x4*)&Vc[vr * 64 + cc1 * 8 + h8];
#pragma unroll
      for (int qm = 0; qm < 4; ++qm)
        accO[qm][nd] = __builtin_amdgcn_mfma_f32_16x16x32_bf16(pa[qm][kk], u.v8, accO[qm][nd], 0, 0, 0);
    }
#pragma unroll
    for (int qm = 0; qm < 4; ++qm)
      acc_l[qm] = __builtin_amdgcn_mfma_f32_16x16x32_bf16(pa[qm][kk], ones, acc_l[qm], 0, 0, 0);
  }
}

__global__ __launch_bounds__(128) void attn_kernel(
    const ushort_t* __restrict__ Qs, const ushort_t* __restrict__ Ks,
    const ushort_t* __restrict__ Vt, ushort_t* __restrict__ Ob)
{
  const int S = 2048;
  const int id = blockIdx.x;                 // 0..511
  const int bh = id & 31;
  const int qt = (id < 256) ? (15 - (id >> 5)) : ((id - 256) >> 5);
  const int l = threadIdx.x & 63;
  const int w = threadIdx.x >> 6;            // 0..1
  const int g = l >> 4, lo = l & 15;

  __shared__ __align__(16) ushort_t Kl[2][64 * 128];  // 2 x 16KB
  __shared__ __align__(16) ushort_t Vl[2][64 * 64];   // 2 x 8KB

  const int qw = qt * 128 + w * 64;          // wave owns 64 q-rows
  const ushort_t* Kbase = Ks + (size_t)bh * S * 128;
  const ushort_t* Vbase = Vt + (size_t)bh * 64 * S;

  bf16x8 ones;
#pragma unroll
  for (int j = 0; j < 8; ++j) ones[j] = (__bf16)1.0f;

  // Q fragments: qf[qm][e] = Q[qw+qm*16+lo][32e+8g .. +7]
  bf16x8 qf[4][4];
#pragma unroll
  for (int qm = 0; qm < 4; ++qm) {
    const ushort_t* qp = Qs + ((size_t)bh * S + qw + qm * 16 + lo) * 128 + 8 * g;
#pragma unroll
    for (int e = 0; e < 4; ++e) qf[qm][e] = *(const bf16x8*)(qp + 32 * e);
  }

  const f32x4 zero4 = {0.f, 0.f, 0.f, 0.f};
  f32x4 accO[4][4];
  f32x4 acc_l[4];
#pragma unroll
  for (int qm = 0; qm < 4; ++qm) {
    acc_l[qm] = zero4;
#pragma unroll
    for (int nd = 0; nd < 4; ++nd) accO[qm][nd] = zero4;
  }

  const int nt = 2 * qt + 2;   // >= 2 always

  // 128 threads: K tile = 8 loads/thread, V tile = 4 loads/thread (12 total)
#define ATTN_STAGE(buf, kb_)                                                    \
  {                                                                             \
    int kb__ = (kb_);                                                           \
    _Pragma("unroll")                                                           \
    for (int i = 0; i < 8; ++i) {                                               \
      int ci = (w * 8 + i) * 64 + l;                                            \
      int r = ci >> 4, c = (ci & 15) ^ (r & 7);                                 \
      gl_lds16(Kbase + (size_t)(kb__ + r) * 128 + c * 8, &Kl[buf][(w * 8 + i) * 512]); \
    }                                                                           \
    _Pragma("unroll")                                                           \
    for (int i = 0; i < 4; ++i) {                                               \
      int ci = (w * 4 + i) * 64 + l;                                            \
      int r = ci >> 3, c = (ci & 7) ^ (r & 7);                                  \
      gl_lds16(Vbase + (size_t)r * S + kb__ + c * 8, &Vl[buf][(w * 4 + i) * 512]); \
    }                                                                           \
  }

  // prologue: stage tiles 0 and 1; confirm tile 0 (12 newest = tile 1 in flight)
  ATTN_STAGE(0, 0);
  ATTN_STAGE(1, 64);
  asm volatile("s_waitcnt vmcnt(12)" ::: "memory");
  __builtin_amdgcn_s_barrier();
  __builtin_amdgcn_sched_barrier(0);

  for (int t = 0; t < nt; ++t) {
    int cb = t & 1;
    __builtin_amdgcn_s_setprio(1);
    if (t < 2 * qt)
      attn_tile<false>(Kl[cb], Vl[cb], qf, accO, acc_l, t * 64, qw, lo, g, ones);
    else
      attn_tile<true>(Kl[cb], Vl[cb], qf, accO, acc_l, t * 64, qw, lo, g, ones);
    __builtin_amdgcn_s_setprio(0);
    __builtin_amdgcn_sched_barrier(0);
    asm volatile("s_waitcnt lgkmcnt(0)" ::: "memory");
    __builtin_amdgcn_s_barrier();            // both waves done reading buf cb
    if (t + 2 < nt) {
      ATTN_STAGE(cb, (t + 2) * 64);          // refill the buffer just freed
      asm volatile("s_waitcnt vmcnt(12)" ::: "memory");  // stage(t+1) landed
    } else {
      asm volatile("s_waitcnt vmcnt(0)" ::: "memory");   // tail: drain rest
    }
    __builtin_amdgcn_s_barrier();            // publish stage(t+1) completion
    __builtin_amdgcn_sched_barrier(0);
  }
#undef ATTN_STAGE

  // normalize: acc_l layout == accO layout (row=(l>>4)*4+reg, replicated cols)
  float linv[4][4];
#pragma unroll
  for (int qm = 0; qm < 4; ++qm)
#pragma unroll
    for (int reg = 0; reg < 4; ++reg)
      linv[qm][reg] = 1.0f / acc_l[qm][reg];

  const int b = bh >> 4, h = bh & 15;
#pragma unroll
  for (int qm = 0; qm < 4; ++qm)
#pragma unroll
    for (int nd = 0; nd < 4; ++nd)
#pragma unroll
      for (int reg = 0; reg < 4; ++reg) {
        int q = qw + qm * 16 + g * 4 + reg;
        int d = nd * 16 + lo;
        Ob[((size_t)(b * 2048 + q)) * 1024 + h * 64 + d] = f2bf(accO[qm][nd][reg] * linv[qm][reg]);
      }
}

// ---------------------------------------------------------------- launch ----
extern "C" void kernel_launch(void* const* d_in, const int* in_sizes, int n_in,
                              void* d_out, int out_size, void* d_ws, size_t ws_size,
                              hipStream_t stream) {
  const float* x  = (const float*)d_in[0];
  const float* wq = (const float*)d_in[1];
  const float* bq = (const float*)d_in[2];
  const float* wk = (const float*)d_in[3];
  const float* bk = (const float*)d_in[4];
  const float* vw = (const float*)d_in[5];
  const float* ow = (const float*)d_in[6];
  float* out = (float*)d_out;

  char* ws = (char*)d_ws;
  ushort_t* Qs  = (ushort_t*)(ws);                      // 16 MB  [32][2048][128]
  ushort_t* Ksb = (ushort_t*)(ws + (16u << 20));        // 16 MB  [32][2048][128]
  ushort_t* Vtb = (ushort_t*)(ws + (32u << 20));        //  8 MB  [32][64][2048]
  ushort_t* xbb = (ushort_t*)(ws + (40u << 20));        //  8 MB  [4096][1024]
  ushort_t* Obb = (ushort_t*)(ws + (48u << 20));        //  8 MB  [4096][1024]
  ushort_t* vwb = (ushort_t*)(ws + (56u << 20));        //  2 MB
  ushort_t* owb = (ushort_t*)(ws + (58u << 20));        //  2 MB

  prep_kernel<<<512, 256, 0, stream>>>(x, wq, bq, wk, bk, Qs, Ksb, xbb);
  wconv_kernel<<<1024, 256, 0, stream>>>(vw, ow, vwb, owb);
  gemm_nt<1><<<512, 256, 0, stream>>>(vwb, xbb, nullptr, Vtb, 1024, 4096, 1024);
  attn_kernel<<<512, 128, 0, stream>>>(Qs, Ksb, Vtb, Obb);
  gemm_nt<0><<<512, 256, 0, stream>>>(Obb, owb, out, nullptr, 4096, 1024, 1024);
}

// Round 13
// 112.495 us; speedup vs baseline: 1.0519x; 1.0519x over previous
//
#include <hip/hip_runtime.h>
#include <hip/hip_bf16.h>
#include <math.h>

// EulerCausalAttention on MI355X (gfx950).
// prep ; wconv ; V-GEMM -> Vt ; causal flash attention (1024 blocks of 2 waves,
// 64 q-rows/block, k split across waves, WAVE-PRIVATE LDS staging -> zero
// barriers in the k-loop, per-wave counted vmcnt, end-of-block partial merge) ;
// out-GEMM (64x128 tiles, counted-vmcnt). All matmuls bf16 MFMA 16x16x32.

typedef __attribute__((ext_vector_type(8))) __bf16 bf16x8;
typedef __attribute__((ext_vector_type(4))) __bf16 bf16x4;
typedef __attribute__((ext_vector_type(4))) float f32x4;
typedef unsigned short ushort_t;
typedef unsigned int uint_t;

#define LUTC 651.8986469044033f       // 4096 / (2*pi)
#define ANG 0.0015339807878856412f    // 2*pi / 4096
#define QSCL 0.12751743590489435f     // log2(e) / sqrt(128)  (folded into Q)

__device__ __forceinline__ float fast_exp2(float x) {
#if __has_builtin(__builtin_amdgcn_exp2f)
  return __builtin_amdgcn_exp2f(x);
#else
  return exp2f(x);
#endif
}

__device__ __forceinline__ ushort_t f2bf(float f) {
  union { __bf16 b; ushort_t u; } cv;
  cv.b = (__bf16)f;
  return cv.u;
}

__device__ __forceinline__ void store8(ushort_t* p, const ushort_t v[8]) {
  uint4 u;
  u.x = (uint_t)v[0] | ((uint_t)v[1] << 16);
  u.y = (uint_t)v[2] | ((uint_t)v[3] << 16);
  u.z = (uint_t)v[4] | ((uint_t)v[5] << 16);
  u.w = (uint_t)v[6] | ((uint_t)v[7] << 16);
  *(uint4*)p = u;
}

__device__ __forceinline__ void gl_lds16(const void* g, void* l) {
  __builtin_amdgcn_global_load_lds(
      (__attribute__((address_space(1))) void*)(g),
      (__attribute__((address_space(3))) void*)(l),
      16, 0, 0);
}

// ---------------------------------------------------------------- prep ------
__global__ __launch_bounds__(256) void prep_kernel(
    const float* __restrict__ x, const float* __restrict__ wq, const float* __restrict__ bq,
    const float* __restrict__ wk, const float* __restrict__ bk,
    ushort_t* __restrict__ Qs, ushort_t* __restrict__ Ks, ushort_t* __restrict__ xb)
{
  int t = blockIdx.x * 256 + threadIdx.x;   // 131072 threads
  int dm8 = t & 127;
  int g = t >> 7;                            // token group of 4
  int dm0 = dm8 * 8;
  int h = dm0 >> 6;

  float aq[8], cq[8], ak[8], ck[8];
#pragma unroll
  for (int j = 0; j < 8; ++j) {
    aq[j] = LUTC / (1.0f + fabsf(wq[dm0 + j]));
    cq[j] = LUTC * bq[dm0 + j];
    ak[j] = LUTC / (1.0f + fabsf(wk[dm0 + j]));
    ck[j] = LUTC * bk[dm0 + j];
  }
  for (int i = 0; i < 4; ++i) {
    int bs = g * 4 + i;
    int b = bs >> 11, s = bs & 2047;
    const float4* xp4 = (const float4*)(x + (size_t)bs * 1024 + dm0);
    float4 xa = xp4[0], xbv4 = xp4[1];
    float xv[8] = {xa.x, xa.y, xa.z, xa.w, xbv4.x, xbv4.y, xbv4.z, xbv4.w};
    ushort_t qc[8], qs[8], kc[8], ks[8], xo[8];
#pragma unroll
    for (int j = 0; j < 8; ++j) {
      int iq = ((int)rintf(fmaf(xv[j], aq[j], cq[j]))) & 4095;
      float sq, cqv;
      __sincosf((float)iq * ANG, &sq, &cqv);
      int ik = ((int)rintf(fmaf(xv[j], ak[j], ck[j]))) & 4095;
      float sk, ckv;
      __sincosf((float)ik * ANG, &sk, &ckv);
      qc[j] = f2bf(cqv * QSCL);
      qs[j] = f2bf(sq * QSCL);
      kc[j] = f2bf(ckv);
      ks[j] = f2bf(sk);
      xo[j] = f2bf(xv[j]);
    }
    size_t qb = ((size_t)(b * 16 + h) * 2048 + s) * 128 + (dm0 & 63);
    store8(Qs + qb, qc);        store8(Qs + qb + 64, qs);
    store8(Ks + qb, kc);        store8(Ks + qb + 64, ks);
    store8(xb + (size_t)bs * 1024 + dm0, xo);
  }
}

// ---------------------------------------------------------------- wconv -----
__global__ __launch_bounds__(256) void wconv_kernel(
    const float* __restrict__ vw, const float* __restrict__ ow,
    ushort_t* __restrict__ vwb, ushort_t* __restrict__ owb)
{
  int t = blockIdx.x * 256 + threadIdx.x;   // 262144 threads
  const float* src;
  ushort_t* dst;
  int i;
  if (t < 131072) { src = vw; dst = vwb; i = t; }
  else            { src = ow; dst = owb; i = t - 131072; }
  const float4* p4 = (const float4*)(src + (size_t)i * 8);
  float4 a = p4[0], b = p4[1];
  float v[8] = {a.x, a.y, a.z, a.w, b.x, b.y, b.z, b.w};
  ushort_t o[8];
#pragma unroll
  for (int j = 0; j < 8; ++j) o[j] = f2bf(v[j]);
  store8(dst + (size_t)i * 8, o);
}

// ---------------------------------------------------------------- GEMM ------
// Tile 64(m) x 128(n), 4 waves, K-step 64, 512 blocks = 2/CU, counted-vmcnt.
template <int EPI>
__global__ __launch_bounds__(256) void gemm_nt(
    const ushort_t* __restrict__ A, const ushort_t* __restrict__ B,
    float* __restrict__ Cf, ushort_t* __restrict__ Cb, int M, int N, int K)
{
  __shared__ __align__(16) ushort_t As[2][64 * 64];    // 2 x 8KB
  __shared__ __align__(16) ushort_t Bs[2][128 * 64];   // 2 x 16KB
  const int l = threadIdx.x & 63;
  const int w = threadIdx.x >> 6;
  const int g = l >> 4, lo = l & 15;
  const int mt = blockIdx.x % (M >> 6);
  const int nt = blockIdx.x / (M >> 6);
  const int m0 = mt << 6, n0 = nt << 7;

  const f32x4 zero4 = {0.f, 0.f, 0.f, 0.f};
  f32x4 acc[4][2];
#pragma unroll
  for (int i = 0; i < 4; ++i)
#pragma unroll
    for (int j = 0; j < 2; ++j) acc[i][j] = zero4;

  const int nk = K >> 6;   // 16 for K=1024

#define GEMM_STAGE(buf, k0_)                                                    \
  {                                                                             \
    int k0__ = (k0_);                                                           \
    _Pragma("unroll")                                                           \
    for (int i = 0; i < 2; ++i) {                                               \
      int ci = (w * 2 + i) * 64 + l;                                            \
      int r = ci >> 3, c = (ci & 7) ^ (r & 7);                                  \
      gl_lds16(A + (size_t)(m0 + r) * K + k0__ + c * 8, &As[buf][(w * 2 + i) * 512]); \
    }                                                                           \
    _Pragma("unroll")                                                           \
    for (int i = 0; i < 4; ++i) {                                               \
      int ci = (w * 4 + i) * 64 + l;                                            \
      int r = ci >> 3, c = (ci & 7) ^ (r & 7);                                  \
      gl_lds16(B + (size_t)(n0 + r) * K + k0__ + c * 8, &Bs[buf][(w * 4 + i) * 512]); \
    }                                                                           \
  }

  GEMM_STAGE(0, 0);
  GEMM_STAGE(1, 64);
  asm volatile("s_waitcnt vmcnt(6)" ::: "memory");   // tile 0 landed
  __builtin_amdgcn_s_barrier();
  __builtin_amdgcn_sched_barrier(0);

  for (int t = 0; t < nk; ++t) {
    int cb = t & 1;
#pragma unroll
    for (int kk = 0; kk < 2; ++kk) {
      bf16x8 af[4], bfr[2];
#pragma unroll
      for (int mi = 0; mi < 4; ++mi) {
        int r = mi * 16 + lo;
        int ch = (g + 4 * kk) ^ (r & 7);
        af[mi] = *(const bf16x8*)&As[cb][r * 64 + ch * 8];
      }
#pragma unroll
      for (int ni = 0; ni < 2; ++ni) {
        int r = w * 32 + ni * 16 + lo;
        int ch = (g + 4 * kk) ^ (r & 7);
        bfr[ni] = *(const bf16x8*)&Bs[cb][r * 64 + ch * 8];
      }
#pragma unroll
      for (int mi = 0; mi < 4; ++mi)
#pragma unroll
        for (int ni = 0; ni < 2; ++ni)
          acc[mi][ni] = __builtin_amdgcn_mfma_f32_16x16x32_bf16(af[mi], bfr[ni], acc[mi][ni], 0, 0, 0);
    }
    __builtin_amdgcn_sched_barrier(0);
    asm volatile("s_waitcnt lgkmcnt(0)" ::: "memory");
    __builtin_amdgcn_s_barrier();                    // all waves done reading cb
    if (t + 2 < nk) {
      GEMM_STAGE(cb, (t + 2) * 64);
      asm volatile("s_waitcnt vmcnt(6)" ::: "memory");  // tile t+1 landed
    } else {
      asm volatile("s_waitcnt vmcnt(0)" ::: "memory");
    }
    __builtin_amdgcn_s_barrier();
    __builtin_amdgcn_sched_barrier(0);
  }
#undef GEMM_STAGE

#pragma unroll
  for (int mi = 0; mi < 4; ++mi)
#pragma unroll
    for (int ni = 0; ni < 2; ++ni)
#pragma unroll
      for (int reg = 0; reg < 4; ++reg) {
        int row = m0 + mi * 16 + g * 4 + reg;
        int col = n0 + w * 32 + ni * 16 + lo;
        float v = acc[mi][ni][reg];
        if (EPI == 0) {
          Cf[(size_t)row * N + col] = v;
        } else {
          size_t o = (size_t)(col >> 11) * (1024 * 2048) + (size_t)row * 2048 + (col & 2047);
          Cb[o] = f2bf(v);
        }
      }
}

// ------------------------------------------------------------- attention ----
// 1024 blocks x 128 threads. Block = (bh, 64-row q-tile qv), launched heavy-
// first (qv descending). The 2 waves split k: wave kh owns the 32-k strip of
// each 64-k tile, staged into WAVE-PRIVATE LDS (K 32x128 8KB + V 64x32 4KB,
// dbuf = 24KB/wave, 48KB/block -> 3 blocks/CU). A wave reads only LDS it
// staged itself -> per-wave counted vmcnt, NO barriers in the k-loop.
// End of block: one barrier, wave-1 partials merged via LDS, wave-0 writes.

template<bool MASKED>
__device__ __forceinline__ void attn_step_kh(
    const ushort_t* __restrict__ Kc, const ushort_t* __restrict__ Vc,
    const bf16x8 (&qf)[4][4], f32x4 (&accO)[4][4], f32x4 (&acc_l)[4],
    int kb_glob, int q0, int lo, int g, const bf16x8& ones)
{
  const f32x4 zero4 = {0.f, 0.f, 0.f, 0.f};
  bf16x8 pa[4];
#pragma unroll
  for (int ns = 0; ns < 2; ++ns) {
    f32x4 sc[4];
#pragma unroll
    for (int qm = 0; qm < 4; ++qm) sc[qm] = zero4;
#pragma unroll
    for (int e = 0; e < 4; ++e) {
      int kr = ns * 16 + lo;
      int cc = (g + 4 * e) ^ (kr & 7);
      bf16x8 kf = *(const bf16x8*)&Kc[kr * 128 + cc * 8];
#pragma unroll
      for (int qm = 0; qm < 4; ++qm)
        sc[qm] = __builtin_amdgcn_mfma_f32_16x16x32_bf16(kf, qf[qm][e], sc[qm], 0, 0, 0);
    }
#pragma unroll
    for (int qm = 0; qm < 4; ++qm) {
#pragma unroll
      for (int reg = 0; reg < 4; ++reg) {
        float sv = sc[qm][reg];
        if (MASKED) {
          int ka = kb_glob + ns * 16 + 4 * g + reg;
          int qa = q0 + qm * 16 + lo;
          sv = (ka <= qa) ? sv : -__builtin_inff();
        }
        pa[qm][ns * 4 + reg] = (__bf16)fast_exp2(sv);
      }
    }
  }
  // PV over this wave's 32-k strip: pa elem j <-> k_strip=(j>>2)*16+g*4+(j&3)
#pragma unroll
  for (int nd = 0; nd < 4; ++nd) {
    int vr = nd * 16 + lo;
    int h8 = (g & 1) * 4;
    int cc0 = ((g >> 1)) ^ (vr & 3);
    int cc1 = (2 + (g >> 1)) ^ (vr & 3);
    union { bf16x8 v8; bf16x4 v4[2]; } u;
    u.v4[0] = *(const bf16x4*)&Vc[vr * 32 + cc0 * 8 + h8];
    u.v4[1] = *(const bf16x4*)&Vc[vr * 32 + cc1 * 8 + h8];
#pragma unroll
    for (int qm = 0; qm < 4; ++qm)
      accO[qm][nd] = __builtin_amdgcn_mfma_f32_16x16x32_bf16(pa[qm], u.v8, accO[qm][nd], 0, 0, 0);
  }
#pragma unroll
  for (int qm = 0; qm < 4; ++qm)
    acc_l[qm] = __builtin_amdgcn_mfma_f32_16x16x32_bf16(pa[qm], ones, acc_l[qm], 0, 0, 0);
}

__global__ __launch_bounds__(128) void attn_kernel(
    const ushort_t* __restrict__ Qs, const ushort_t* __restrict__ Ks,
    const ushort_t* __restrict__ Vt, ushort_t* __restrict__ Ob)
{
  const int S = 2048;
  const int id = blockIdx.x;                 // 0..1023
  const int bh = id & 31;
  const int qv = 31 - (id >> 5);             // heavy q-tiles first
  const int nt = qv + 1;                     // k-tiles of 64
  const int q0 = qv * 64;

  const int l = threadIdx.x & 63;
  const int kh = threadIdx.x >> 6;           // wave's k-strip within each tile
  const int g = l >> 4, lo = l & 15;

  // wave-private LDS: per wave [2 dbuf][K 32x128 | V 64x32]
  __shared__ __align__(16) ushort_t Lds[2][2][4096 + 2048];  // 48KB
  ushort_t* Kw[2] = {&Lds[kh][0][0], &Lds[kh][1][0]};
  ushort_t* Vw[2] = {&Lds[kh][0][4096], &Lds[kh][1][4096]};

  const ushort_t* Kbase = Ks + (size_t)bh * S * 128;
  const ushort_t* Vbase = Vt + (size_t)bh * 64 * S;

  bf16x8 ones;
#pragma unroll
  for (int j = 0; j < 8; ++j) ones[j] = (__bf16)1.0f;

  // Q fragments: qf[qm][e] = Q[q0+qm*16+lo][32e+8g .. +7]
  bf16x8 qf[4][4];
#pragma unroll
  for (int qm = 0; qm < 4; ++qm) {
    const ushort_t* qp = Qs + ((size_t)bh * S + q0 + qm * 16 + lo) * 128 + 8 * g;
#pragma unroll
    for (int e = 0; e < 4; ++e) qf[qm][e] = *(const bf16x8*)(qp + 32 * e);
  }

  const f32x4 zero4 = {0.f, 0.f, 0.f, 0.f};
  f32x4 accO[4][4];
  f32x4 acc_l[4];
#pragma unroll
  for (int qm = 0; qm < 4; ++qm) {
    acc_l[qm] = zero4;
#pragma unroll
    for (int nd = 0; nd < 4; ++nd) accO[qm][nd] = zero4;
  }

  // per-wave staging of own strips: 8 K-loads + 4 V-loads = 12 gl_lds16
#define ATTN_STAGE(buf, kb_)                                                    \
  {                                                                             \
    int kb__ = (kb_) + kh * 32;                                                 \
    _Pragma("unroll")                                                           \
    for (int i = 0; i < 8; ++i) {                                               \
      int ci = i * 64 + l;                                                      \
      int r = ci >> 4, c = (ci & 15) ^ (r & 7);                                 \
      gl_lds16(Kbase + (size_t)(kb__ + r) * 128 + c * 8, Kw[buf] + (size_t)(i * 64) * 8); \
    }                                                                           \
    _Pragma("unroll")                                                           \
    for (int i = 0; i < 4; ++i) {                                               \
      int ci = i * 64 + l;                                                      \
      int r = ci >> 2, c = (ci & 3) ^ (r & 3);                                  \
      gl_lds16(Vbase + (size_t)r * S + kb__ + c * 8, Vw[buf] + (size_t)(i * 64) * 8); \
    }                                                                           \
  }

  ATTN_STAGE(0, 0);
  if (nt > 1) {
    ATTN_STAGE(1, 64);
    asm volatile("s_waitcnt vmcnt(12)" ::: "memory");  // tile 0 landed (ours)
  } else {
    asm volatile("s_waitcnt vmcnt(0)" ::: "memory");
  }
  __builtin_amdgcn_sched_barrier(0);

  for (int t = 0; t < nt; ++t) {
    int cb = t & 1;
    if (t < nt - 1)
      attn_step_kh<false>(Kw[cb], Vw[cb], qf, accO, acc_l, t * 64 + kh * 32, q0, lo, g, ones);
    else
      attn_step_kh<true>(Kw[cb], Vw[cb], qf, accO, acc_l, t * 64 + kh * 32, q0, lo, g, ones);
    if (t + 1 < nt) {
      __builtin_amdgcn_sched_barrier(0);
      asm volatile("s_waitcnt lgkmcnt(0)" ::: "memory");   // our ds reads done
      if (t + 2 < nt) {
        ATTN_STAGE(cb, (t + 2) * 64);                      // refill own buffer
        asm volatile("s_waitcnt vmcnt(12)" ::: "memory");  // tile t+1 landed
      } else {
        asm volatile("s_waitcnt vmcnt(0)" ::: "memory");
      }
      __builtin_amdgcn_sched_barrier(0);
    }
  }
#undef ATTN_STAGE

  // ---- merge the two kh-partials (one barrier) ----
  asm volatile("s_waitcnt vmcnt(0) lgkmcnt(0)" ::: "memory");
  __builtin_amdgcn_s_barrier();
  float* cmb = (float*)&Lds[0][0][0];   // alias over staging area
  if (kh == 1) {
#pragma unroll
    for (int qm = 0; qm < 4; ++qm) {
#pragma unroll
      for (int nd = 0; nd < 4; ++nd)
#pragma unroll
        for (int reg = 0; reg < 4; ++reg)
          cmb[l * 68 + qm * 16 + nd * 4 + reg] = accO[qm][nd][reg];
#pragma unroll
      for (int reg = 0; reg < 4; ++reg)
        cmb[l * 68 + 64 + qm] = acc_l[qm][0];   // replicated; reg 0 suffices? no:
    }
    // acc_l[qm][reg] differs per reg (row). store all 16:
#pragma unroll
    for (int qm = 0; qm < 4; ++qm)
#pragma unroll
      for (int reg = 0; reg < 4; ++reg)
        cmb[l * 68 + 64 + 0] = cmb[l * 68 + 64 + 0]; // placeholder (see below)
  }
  __builtin_amdgcn_s_barrier();
  // NOTE: acc_l store done properly below via second area to keep indices clear
  float* cmbl = (float*)&Lds[1][0][0];
  if (kh == 1) {
#pragma unroll
    for (int qm = 0; qm < 4; ++qm)
#pragma unroll
      for (int reg = 0; reg < 4; ++reg)
        cmbl[l * 16 + qm * 4 + reg] = acc_l[qm][reg];
  }
  asm volatile("s_waitcnt lgkmcnt(0)" ::: "memory");
  __builtin_amdgcn_s_barrier();

  if (kh == 0) {
#pragma unroll
    for (int qm = 0; qm < 4; ++qm) {
#pragma unroll
      for (int nd = 0; nd < 4; ++nd)
#pragma unroll
        for (int reg = 0; reg < 4; ++reg)
          accO[qm][nd][reg] += cmb[l * 68 + qm * 16 + nd * 4 + reg];
#pragma unroll
      for (int reg = 0; reg < 4; ++reg)
        acc_l[qm][reg] += cmbl[l * 16 + qm * 4 + reg];
    }
    float linv[4][4];
#pragma unroll
    for (int qm = 0; qm < 4; ++qm)
#pragma unroll
      for (int reg = 0; reg < 4; ++reg)
        linv[qm][reg] = 1.0f / acc_l[qm][reg];

    const int b = bh >> 4, h = bh & 15;
#pragma unroll
    for (int qm = 0; qm < 4; ++qm)
#pragma unroll
      for (int nd = 0; nd < 4; ++nd)
#pragma unroll
        for (int reg = 0; reg < 4; ++reg) {
          int q = q0 + qm * 16 + g * 4 + reg;
          int d = nd * 16 + lo;
          Ob[((size_t)(b * 2048 + q)) * 1024 + h * 64 + d] =
              f2bf(accO[qm][nd][reg] * linv[qm][reg]);
        }
  }
}

// ---------------------------------------------------------------- launch ----
extern "C" void kernel_launch(void* const* d_in, const int* in_sizes, int n_in,
                              void* d_out, int out_size, void* d_ws, size_t ws_size,
                              hipStream_t stream) {
  const float* x  = (const float*)d_in[0];
  const float* wq = (const float*)d_in[1];
  const float* bq = (const float*)d_in[2];
  const float* wk = (const float*)d_in[3];
  const float* bk = (const float*)d_in[4];
  const float* vw = (const float*)d_in[5];
  const float* ow = (const float*)d_in[6];
  float* out = (float*)d_out;

  char* ws = (char*)d_ws;
  ushort_t* Qs  = (ushort_t*)(ws);                      // 16 MB  [32][2048][128]
  ushort_t* Ksb = (ushort_t*)(ws + (16u << 20));        // 16 MB  [32][2048][128]
  ushort_t* Vtb = (ushort_t*)(ws + (32u << 20));        //  8 MB  [32][64][2048]
  ushort_t* xbb = (ushort_t*)(ws + (40u << 20));        //  8 MB  [4096][1024]
  ushort_t* Obb = (ushort_t*)(ws + (48u << 20));        //  8 MB  [4096][1024]
  ushort_t* vwb = (ushort_t*)(ws + (56u << 20));        //  2 MB
  ushort_t* owb = (ushort_t*)(ws + (58u << 20));        //  2 MB

  prep_kernel<<<512, 256, 0, stream>>>(x, wq, bq, wk, bk, Qs, Ksb, xbb);
  wconv_kernel<<<1024, 256, 0, stream>>>(vw, ow, vwb, owb);
  gemm_nt<1><<<512, 256, 0, stream>>>(vwb, xbb, nullptr, Vtb, 1024, 4096, 1024);
  attn_kernel<<<1024, 128, 0, stream>>>(Qs, Ksb, Vtb, Obb);
  gemm_nt<0><<<512, 256, 0, stream>>>(Obb, owb, out, nullptr, 4096, 1024, 1024);
}

// Round 14
// 98.410 us; speedup vs baseline: 1.2025x; 1.1431x over previous
//
#include <hip/hip_runtime.h>
#include <hip/hip_bf16.h>
#include <math.h>

// EulerCausalAttention on MI355X (gfx950).
// prep (Q/K euler features, log2e folded into Q) ; wconv ; V-GEMM -> Vt[b,h,d,s] ;
// causal flash attention (round-10 structure: 4 waves x 32 q-rows, KVBLK=64,
// balanced qt pairing, setprio; NEW: triple-buffered k-loop with ONE barrier
// per step -- stage(t+2) targets the buffer last read at t-1, so the WAR
// barrier is gone) ; out-GEMM. GEMMs: 64x128 tiles + counted-vmcnt (round-10).

typedef __attribute__((ext_vector_type(8))) __bf16 bf16x8;
typedef __attribute__((ext_vector_type(4))) __bf16 bf16x4;
typedef __attribute__((ext_vector_type(4))) float f32x4;
typedef unsigned short ushort_t;
typedef unsigned int uint_t;

#define LUTC 651.8986469044033f       // 4096 / (2*pi)
#define ANG 0.0015339807878856412f    // 2*pi / 4096
#define QSCL 0.12751743590489435f     // log2(e) / sqrt(128)  (folded into Q)

__device__ __forceinline__ float fast_exp2(float x) {
#if __has_builtin(__builtin_amdgcn_exp2f)
  return __builtin_amdgcn_exp2f(x);
#else
  return exp2f(x);
#endif
}

__device__ __forceinline__ ushort_t f2bf(float f) {
  union { __bf16 b; ushort_t u; } cv;
  cv.b = (__bf16)f;
  return cv.u;
}

__device__ __forceinline__ void store8(ushort_t* p, const ushort_t v[8]) {
  uint4 u;
  u.x = (uint_t)v[0] | ((uint_t)v[1] << 16);
  u.y = (uint_t)v[2] | ((uint_t)v[3] << 16);
  u.z = (uint_t)v[4] | ((uint_t)v[5] << 16);
  u.w = (uint_t)v[6] | ((uint_t)v[7] << 16);
  *(uint4*)p = u;
}

__device__ __forceinline__ void gl_lds16(const void* g, void* l) {
  __builtin_amdgcn_global_load_lds(
      (__attribute__((address_space(1))) void*)(g),
      (__attribute__((address_space(3))) void*)(l),
      16, 0, 0);
}

// ---------------------------------------------------------------- prep ------
__global__ __launch_bounds__(256) void prep_kernel(
    const float* __restrict__ x, const float* __restrict__ wq, const float* __restrict__ bq,
    const float* __restrict__ wk, const float* __restrict__ bk,
    ushort_t* __restrict__ Qs, ushort_t* __restrict__ Ks, ushort_t* __restrict__ xb)
{
  int t = blockIdx.x * 256 + threadIdx.x;   // 131072 threads
  int dm8 = t & 127;
  int g = t >> 7;                            // token group of 4
  int dm0 = dm8 * 8;
  int h = dm0 >> 6;

  float aq[8], cq[8], ak[8], ck[8];
#pragma unroll
  for (int j = 0; j < 8; ++j) {
    aq[j] = LUTC / (1.0f + fabsf(wq[dm0 + j]));
    cq[j] = LUTC * bq[dm0 + j];
    ak[j] = LUTC / (1.0f + fabsf(wk[dm0 + j]));
    ck[j] = LUTC * bk[dm0 + j];
  }
  for (int i = 0; i < 4; ++i) {
    int bs = g * 4 + i;
    int b = bs >> 11, s = bs & 2047;
    const float4* xp4 = (const float4*)(x + (size_t)bs * 1024 + dm0);
    float4 xa = xp4[0], xbv4 = xp4[1];
    float xv[8] = {xa.x, xa.y, xa.z, xa.w, xbv4.x, xbv4.y, xbv4.z, xbv4.w};
    ushort_t qc[8], qs[8], kc[8], ks[8], xo[8];
#pragma unroll
    for (int j = 0; j < 8; ++j) {
      int iq = ((int)rintf(fmaf(xv[j], aq[j], cq[j]))) & 4095;
      float sq, cqv;
      __sincosf((float)iq * ANG, &sq, &cqv);
      int ik = ((int)rintf(fmaf(xv[j], ak[j], ck[j]))) & 4095;
      float sk, ckv;
      __sincosf((float)ik * ANG, &sk, &ckv);
      qc[j] = f2bf(cqv * QSCL);
      qs[j] = f2bf(sq * QSCL);
      kc[j] = f2bf(ckv);
      ks[j] = f2bf(sk);
      xo[j] = f2bf(xv[j]);
    }
    size_t qb = ((size_t)(b * 16 + h) * 2048 + s) * 128 + (dm0 & 63);
    store8(Qs + qb, qc);        store8(Qs + qb + 64, qs);
    store8(Ks + qb, kc);        store8(Ks + qb + 64, ks);
    store8(xb + (size_t)bs * 1024 + dm0, xo);
  }
}

// ---------------------------------------------------------------- wconv -----
__global__ __launch_bounds__(256) void wconv_kernel(
    const float* __restrict__ vw, const float* __restrict__ ow,
    ushort_t* __restrict__ vwb, ushort_t* __restrict__ owb)
{
  int t = blockIdx.x * 256 + threadIdx.x;   // 262144 threads
  const float* src;
  ushort_t* dst;
  int i;
  if (t < 131072) { src = vw; dst = vwb; i = t; }
  else            { src = ow; dst = owb; i = t - 131072; }
  const float4* p4 = (const float4*)(src + (size_t)i * 8);
  float4 a = p4[0], b = p4[1];
  float v[8] = {a.x, a.y, a.z, a.w, b.x, b.y, b.z, b.w};
  ushort_t o[8];
#pragma unroll
  for (int j = 0; j < 8; ++j) o[j] = f2bf(v[j]);
  store8(dst + (size_t)i * 8, o);
}

// ---------------------------------------------------------------- GEMM ------
// Tile 64(m) x 128(n), 4 waves, K-step 64, 512 blocks = 2/CU, counted-vmcnt.
template <int EPI>
__global__ __launch_bounds__(256) void gemm_nt(
    const ushort_t* __restrict__ A, const ushort_t* __restrict__ B,
    float* __restrict__ Cf, ushort_t* __restrict__ Cb, int M, int N, int K)
{
  __shared__ __align__(16) ushort_t As[2][64 * 64];    // 2 x 8KB
  __shared__ __align__(16) ushort_t Bs[2][128 * 64];   // 2 x 16KB
  const int l = threadIdx.x & 63;
  const int w = threadIdx.x >> 6;
  const int g = l >> 4, lo = l & 15;
  const int mt = blockIdx.x % (M >> 6);
  const int nt = blockIdx.x / (M >> 6);
  const int m0 = mt << 6, n0 = nt << 7;

  const f32x4 zero4 = {0.f, 0.f, 0.f, 0.f};
  f32x4 acc[4][2];
#pragma unroll
  for (int i = 0; i < 4; ++i)
#pragma unroll
    for (int j = 0; j < 2; ++j) acc[i][j] = zero4;

  const int nk = K >> 6;   // 16 for K=1024

#define GEMM_STAGE(buf, k0_)                                                    \
  {                                                                             \
    int k0__ = (k0_);                                                           \
    _Pragma("unroll")                                                           \
    for (int i = 0; i < 2; ++i) {                                               \
      int ci = (w * 2 + i) * 64 + l;                                            \
      int r = ci >> 3, c = (ci & 7) ^ (r & 7);                                  \
      gl_lds16(A + (size_t)(m0 + r) * K + k0__ + c * 8, &As[buf][(w * 2 + i) * 512]); \
    }                                                                           \
    _Pragma("unroll")                                                           \
    for (int i = 0; i < 4; ++i) {                                               \
      int ci = (w * 4 + i) * 64 + l;                                            \
      int r = ci >> 3, c = (ci & 7) ^ (r & 7);                                  \
      gl_lds16(B + (size_t)(n0 + r) * K + k0__ + c * 8, &Bs[buf][(w * 4 + i) * 512]); \
    }                                                                           \
  }

  GEMM_STAGE(0, 0);
  GEMM_STAGE(1, 64);
  asm volatile("s_waitcnt vmcnt(6)" ::: "memory");   // tile 0 landed
  __builtin_amdgcn_s_barrier();
  __builtin_amdgcn_sched_barrier(0);

  for (int t = 0; t < nk; ++t) {
    int cb = t & 1;
#pragma unroll
    for (int kk = 0; kk < 2; ++kk) {
      bf16x8 af[4], bfr[2];
#pragma unroll
      for (int mi = 0; mi < 4; ++mi) {
        int r = mi * 16 + lo;
        int ch = (g + 4 * kk) ^ (r & 7);
        af[mi] = *(const bf16x8*)&As[cb][r * 64 + ch * 8];
      }
#pragma unroll
      for (int ni = 0; ni < 2; ++ni) {
        int r = w * 32 + ni * 16 + lo;
        int ch = (g + 4 * kk) ^ (r & 7);
        bfr[ni] = *(const bf16x8*)&Bs[cb][r * 64 + ch * 8];
      }
#pragma unroll
      for (int mi = 0; mi < 4; ++mi)
#pragma unroll
        for (int ni = 0; ni < 2; ++ni)
          acc[mi][ni] = __builtin_amdgcn_mfma_f32_16x16x32_bf16(af[mi], bfr[ni], acc[mi][ni], 0, 0, 0);
    }
    __builtin_amdgcn_sched_barrier(0);
    asm volatile("s_waitcnt lgkmcnt(0)" ::: "memory");
    __builtin_amdgcn_s_barrier();                    // all waves done reading cb
    if (t + 2 < nk) {
      GEMM_STAGE(cb, (t + 2) * 64);
      asm volatile("s_waitcnt vmcnt(6)" ::: "memory");  // tile t+1 landed
    } else {
      asm volatile("s_waitcnt vmcnt(0)" ::: "memory");
    }
    __builtin_amdgcn_s_barrier();
    __builtin_amdgcn_sched_barrier(0);
  }
#undef GEMM_STAGE

#pragma unroll
  for (int mi = 0; mi < 4; ++mi)
#pragma unroll
    for (int ni = 0; ni < 2; ++ni)
#pragma unroll
      for (int reg = 0; reg < 4; ++reg) {
        int row = m0 + mi * 16 + g * 4 + reg;
        int col = n0 + w * 32 + ni * 16 + lo;
        float v = acc[mi][ni][reg];
        if (EPI == 0) {
          Cf[(size_t)row * N + col] = v;
        } else {
          size_t o = (size_t)(col >> 11) * (1024 * 2048) + (size_t)row * 2048 + (col & 2047);
          Cb[o] = f2bf(v);
        }
      }
}

// ------------------------------------------------------------- attention ----
// Round-10 structure: 512 blocks x 256 threads, 4 waves x 32 q-rows, QBLK=128,
// KVBLK=64, balanced qt pairing, setprio around compute.
// NEW: TRIPLE-buffer + ONE barrier/step. stage(t+2) -> buf[(t+2)%3], which was
// last read at step t-1; all waves' t-1 reads completed before the t-1 barrier
// (each wave drains its own lgkm pre-barrier), so no WAR barrier is needed.
// Per step: compute(buf[t%3]) ; stage(t+2) ; lgkmcnt(0) ; vmcnt(6) ; barrier.

template<bool MASKED>
__device__ __forceinline__ void attn_tile(
    const ushort_t* __restrict__ Kc, const ushort_t* __restrict__ Vc,
    const bf16x8 (&qf)[2][4], f32x4 (&accO)[2][4], f32x4 (&acc_l)[2],
    int kb, int qw, int lo, int g, const bf16x8& ones)
{
  const f32x4 zero4 = {0.f, 0.f, 0.f, 0.f};
  f32x4 sc[2][4];
#pragma unroll
  for (int qm = 0; qm < 2; ++qm)
#pragma unroll
    for (int ns = 0; ns < 4; ++ns) sc[qm][ns] = zero4;

  // S^T tile: lane holds S[q=qw+qm*16+lo][k=kb+ns*16+g*4+reg]
#pragma unroll
  for (int e = 0; e < 4; ++e) {
#pragma unroll
    for (int ns = 0; ns < 4; ++ns) {
      int kr = ns * 16 + lo;
      int cc = (g + 4 * e) ^ (kr & 7);
      bf16x8 kf = *(const bf16x8*)&Kc[kr * 128 + cc * 8];
#pragma unroll
      for (int qm = 0; qm < 2; ++qm)
        sc[qm][ns] = __builtin_amdgcn_mfma_f32_16x16x32_bf16(kf, qf[qm][e], sc[qm][ns], 0, 0, 0);
    }
  }

  // p = exp2(s), pack to PV A-fragments (registers only)
  bf16x8 pa[2][2];
#pragma unroll
  for (int qm = 0; qm < 2; ++qm) {
#pragma unroll
    for (int ns = 0; ns < 4; ++ns) {
#pragma unroll
      for (int reg = 0; reg < 4; ++reg) {
        float sv = sc[qm][ns][reg];
        if (MASKED) {
          int ka = kb + ns * 16 + g * 4 + reg;
          int qa = qw + qm * 16 + lo;
          sv = (ka <= qa) ? sv : -__builtin_inff();
        }
        pa[qm][ns >> 1][(ns & 1) * 4 + reg] = (__bf16)fast_exp2(sv);
      }
    }
  }

  // O += P V ; rowsum += P * ones
#pragma unroll
  for (int kk = 0; kk < 2; ++kk) {
#pragma unroll
    for (int nd = 0; nd < 4; ++nd) {
      int vr = nd * 16 + lo;
      int h8 = (g & 1) * 4;
      int cc0 = (4 * kk + (g >> 1)) ^ (vr & 7);
      int cc1 = (4 * kk + 2 + (g >> 1)) ^ (vr & 7);
      union { bf16x8 v8; bf16x4 v4[2]; } u;
      u.v4[0] = *(const bf16x4*)&Vc[vr * 64 + cc0 * 8 + h8];
      u.v4[1] = *(const bf16x4*)&Vc[vr * 64 + cc1 * 8 + h8];
#pragma unroll
      for (int qm = 0; qm < 2; ++qm)
        accO[qm][nd] = __builtin_amdgcn_mfma_f32_16x16x32_bf16(pa[qm][kk], u.v8, accO[qm][nd], 0, 0, 0);
    }
#pragma unroll
    for (int qm = 0; qm < 2; ++qm)
      acc_l[qm] = __builtin_amdgcn_mfma_f32_16x16x32_bf16(pa[qm][kk], ones, acc_l[qm], 0, 0, 0);
  }
}

__global__ __launch_bounds__(256) void attn_kernel(
    const ushort_t* __restrict__ Qs, const ushort_t* __restrict__ Ks,
    const ushort_t* __restrict__ Vt, ushort_t* __restrict__ Ob)
{
  const int S = 2048;
  const int id = blockIdx.x;                 // 0..511
  const int bh = id & 31;
  const int qt = (id < 256) ? (15 - (id >> 5)) : ((id - 256) >> 5);
  const int l = threadIdx.x & 63;
  const int w = threadIdx.x >> 6;
  const int g = l >> 4, lo = l & 15;

  __shared__ __align__(16) ushort_t Kl[3][64 * 128];  // 3 x 16KB
  __shared__ __align__(16) ushort_t Vl[3][64 * 64];   // 3 x 8KB  (72KB total)

  const int q0b = qt * 128;
  const int qw = q0b + w * 32;
  const ushort_t* Kbase = Ks + (size_t)bh * S * 128;
  const ushort_t* Vbase = Vt + (size_t)bh * 64 * S;

  bf16x8 ones;
#pragma unroll
  for (int j = 0; j < 8; ++j) ones[j] = (__bf16)1.0f;

  // Q fragments: qf[qm][e] = Q[qw+qm*16+lo][32e+8g .. +7]
  bf16x8 qf[2][4];
#pragma unroll
  for (int qm = 0; qm < 2; ++qm) {
    const ushort_t* qp = Qs + ((size_t)bh * S + qw + qm * 16 + lo) * 128 + 8 * g;
#pragma unroll
    for (int e = 0; e < 4; ++e) qf[qm][e] = *(const bf16x8*)(qp + 32 * e);
  }

  const f32x4 zero4 = {0.f, 0.f, 0.f, 0.f};
  f32x4 accO[2][4];
  f32x4 acc_l[2];
#pragma unroll
  for (int qm = 0; qm < 2; ++qm) {
    acc_l[qm] = zero4;
#pragma unroll
    for (int nd = 0; nd < 4; ++nd) accO[qm][nd] = zero4;
  }

  const int nt = 2 * qt + 2;   // >= 2 always

#define ATTN_STAGE(buf, kb_)                                                    \
  {                                                                             \
    int kb__ = (kb_);                                                           \
    _Pragma("unroll")                                                           \
    for (int i = 0; i < 4; ++i) {                                               \
      int ci = (w * 4 + i) * 64 + l;                                            \
      int r = ci >> 4, c = (ci & 15) ^ (r & 7);                                 \
      gl_lds16(Kbase + (size_t)(kb__ + r) * 128 + c * 8, &Kl[buf][(w * 4 + i) * 512]); \
    }                                                                           \
    _Pragma("unroll")                                                           \
    for (int i = 0; i < 2; ++i) {                                               \
      int ci = (w * 2 + i) * 64 + l;                                            \
      int r = ci >> 3, c = (ci & 7) ^ (r & 7);                                  \
      gl_lds16(Vbase + (size_t)r * S + kb__ + c * 8, &Vl[buf][(w * 2 + i) * 512]); \
    }                                                                           \
  }

  // prologue: stage tiles 0,1 into buf 0,1; confirm tile 0 (6 newest in flight)
  ATTN_STAGE(0, 0);
  ATTN_STAGE(1, 64);
  asm volatile("s_waitcnt vmcnt(6)" ::: "memory");
  __builtin_amdgcn_s_barrier();
  __builtin_amdgcn_sched_barrier(0);

  int rb = 0;                     // t % 3
  int wb = 2;                     // (t+2) % 3
  for (int t = 0; t < nt; ++t) {
    __builtin_amdgcn_s_setprio(1);
    if (t < 2 * qt)
      attn_tile<false>(Kl[rb], Vl[rb], qf, accO, acc_l, t * 64, qw, lo, g, ones);
    else
      attn_tile<true>(Kl[rb], Vl[rb], qf, accO, acc_l, t * 64, qw, lo, g, ones);
    __builtin_amdgcn_s_setprio(0);
    __builtin_amdgcn_sched_barrier(0);
    if (t + 2 < nt) {
      ATTN_STAGE(wb, (t + 2) * 64);          // buffer last read at t-1: WAR-safe
      asm volatile("s_waitcnt lgkmcnt(0)" ::: "memory");  // own reads of rb done
      asm volatile("s_waitcnt vmcnt(6)" ::: "memory");    // own stage(t+1) landed
    } else if (t + 1 < nt) {
      asm volatile("s_waitcnt lgkmcnt(0)" ::: "memory");
      asm volatile("s_waitcnt vmcnt(0)" ::: "memory");    // tail: drain rest
    }
    if (t + 1 < nt) {
      __builtin_amdgcn_s_barrier();          // publish stage(t+1) completion
      __builtin_amdgcn_sched_barrier(0);
    }
    rb = (rb == 2) ? 0 : rb + 1;
    wb = (wb == 2) ? 0 : wb + 1;
  }
#undef ATTN_STAGE

  // normalize: acc_l layout == accO layout (row=(l>>4)*4+reg, replicated cols)
  float linv[2][4];
#pragma unroll
  for (int qm = 0; qm < 2; ++qm)
#pragma unroll
    for (int reg = 0; reg < 4; ++reg)
      linv[qm][reg] = 1.0f / acc_l[qm][reg];

  const int b = bh >> 4, h = bh & 15;
#pragma unroll
  for (int qm = 0; qm < 2; ++qm)
#pragma unroll
    for (int nd = 0; nd < 4; ++nd)
#pragma unroll
      for (int reg = 0; reg < 4; ++reg) {
        int q = qw + qm * 16 + g * 4 + reg;
        int d = nd * 16 + lo;
        Ob[((size_t)(b * 2048 + q)) * 1024 + h * 64 + d] = f2bf(accO[qm][nd][reg] * linv[qm][reg]);
      }
}

// ---------------------------------------------------------------- launch ----
extern "C" void kernel_launch(void* const* d_in, const int* in_sizes, int n_in,
                              void* d_out, int out_size, void* d_ws, size_t ws_size,
                              hipStream_t stream) {
  const float* x  = (const float*)d_in[0];
  const float* wq = (const float*)d_in[1];
  const float* bq = (const float*)d_in[2];
  const float* wk = (const float*)d_in[3];
  const float* bk = (const float*)d_in[4];
  const float* vw = (const float*)d_in[5];
  const float* ow = (const float*)d_in[6];
  float* out = (float*)d_out;

  char* ws = (char*)d_ws;
  ushort_t* Qs  = (ushort_t*)(ws);                      // 16 MB  [32][2048][128]
  ushort_t* Ksb = (ushort_t*)(ws + (16u << 20));        // 16 MB  [32][2048][128]
  ushort_t* Vtb = (ushort_t*)(ws + (32u << 20));        //  8 MB  [32][64][2048]
  ushort_t* xbb = (ushort_t*)(ws + (40u << 20));        //  8 MB  [4096][1024]
  ushort_t* Obb = (ushort_t*)(ws + (48u << 20));        //  8 MB  [4096][1024]
  ushort_t* vwb = (ushort_t*)(ws + (56u << 20));        //  2 MB
  ushort_t* owb = (ushort_t*)(ws + (58u << 20));        //  2 MB

  prep_kernel<<<512, 256, 0, stream>>>(x, wq, bq, wk, bk, Qs, Ksb, xbb);
  wconv_kernel<<<1024, 256, 0, stream>>>(vw, ow, vwb, owb);
  gemm_nt<1><<<512, 256, 0, stream>>>(vwb, xbb, nullptr, Vtb, 1024, 4096, 1024);
  attn_kernel<<<512, 256, 0, stream>>>(Qs, Ksb, Vtb, Obb);
  gemm_nt<0><<<512, 256, 0, stream>>>(Obb, owb, out, nullptr, 4096, 1024, 1024);
}

// Round 18
// 94.092 us; speedup vs baseline: 1.2577x; 1.0459x over previous
//
#include <hip/hip_runtime.h>
#include <hip/hip_bf16.h>
#include <math.h>

// EulerCausalAttention on MI355X (gfx950).
// prep+wconv (fused) ; V-GEMM -> Vt ; causal flash attention (round-14:
// 4 waves x 32 q-rows, KVBLK=64, balanced qt pairing, TRIPLE-buffer
// single-barrier k-loop, setprio) ; out-GEMM.
// NEW this round: GEMMs also use the triple-buffer single-barrier loop;
// wconv fused into prep (one fewer dispatch).

typedef __attribute__((ext_vector_type(8))) __bf16 bf16x8;
typedef __attribute__((ext_vector_type(4))) __bf16 bf16x4;
typedef __attribute__((ext_vector_type(4))) float f32x4;
typedef unsigned short ushort_t;
typedef unsigned int uint_t;

#define LUTC 651.8986469044033f       // 4096 / (2*pi)
#define ANG 0.0015339807878856412f    // 2*pi / 4096
#define QSCL 0.12751743590489435f     // log2(e) / sqrt(128)  (folded into Q)

__device__ __forceinline__ float fast_exp2(float x) {
#if __has_builtin(__builtin_amdgcn_exp2f)
  return __builtin_amdgcn_exp2f(x);
#else
  return exp2f(x);
#endif
}

__device__ __forceinline__ ushort_t f2bf(float f) {
  union { __bf16 b; ushort_t u; } cv;
  cv.b = (__bf16)f;
  return cv.u;
}

__device__ __forceinline__ void store8(ushort_t* p, const ushort_t v[8]) {
  uint4 u;
  u.x = (uint_t)v[0] | ((uint_t)v[1] << 16);
  u.y = (uint_t)v[2] | ((uint_t)v[3] << 16);
  u.z = (uint_t)v[4] | ((uint_t)v[5] << 16);
  u.w = (uint_t)v[6] | ((uint_t)v[7] << 16);
  *(uint4*)p = u;
}

__device__ __forceinline__ void gl_lds16(const void* g, void* l) {
  __builtin_amdgcn_global_load_lds(
      (__attribute__((address_space(1))) void*)(g),
      (__attribute__((address_space(3))) void*)(l),
      16, 0, 0);
}

// ------------------------------------------------------- prep + wconv -------
// blocks 0..511: euler-feature prep (as round-14). blocks 512..1535: weight
// conversion f32->bf16 (the old wconv_kernel). Disjoint data, block-granular.
__global__ __launch_bounds__(256) void prep_kernel(
    const float* __restrict__ x, const float* __restrict__ wq, const float* __restrict__ bq,
    const float* __restrict__ wk, const float* __restrict__ bk,
    ushort_t* __restrict__ Qs, ushort_t* __restrict__ Ks, ushort_t* __restrict__ xb,
    const float* __restrict__ vw, const float* __restrict__ ow,
    ushort_t* __restrict__ vwb, ushort_t* __restrict__ owb)
{
  if (blockIdx.x >= 512) {
    int t = (blockIdx.x - 512) * 256 + threadIdx.x;   // 262144 threads
    const float* src;
    ushort_t* dst;
    int i;
    if (t < 131072) { src = vw; dst = vwb; i = t; }
    else            { src = ow; dst = owb; i = t - 131072; }
    const float4* p4 = (const float4*)(src + (size_t)i * 8);
    float4 a = p4[0], b = p4[1];
    float v[8] = {a.x, a.y, a.z, a.w, b.x, b.y, b.z, b.w};
    ushort_t o[8];
#pragma unroll
    for (int j = 0; j < 8; ++j) o[j] = f2bf(v[j]);
    store8(dst + (size_t)i * 8, o);
    return;
  }

  int t = blockIdx.x * 256 + threadIdx.x;   // 131072 threads
  int dm8 = t & 127;
  int g = t >> 7;                            // token group of 4
  int dm0 = dm8 * 8;
  int h = dm0 >> 6;

  float aq[8], cq[8], ak[8], ck[8];
#pragma unroll
  for (int j = 0; j < 8; ++j) {
    aq[j] = LUTC / (1.0f + fabsf(wq[dm0 + j]));
    cq[j] = LUTC * bq[dm0 + j];
    ak[j] = LUTC / (1.0f + fabsf(wk[dm0 + j]));
    ck[j] = LUTC * bk[dm0 + j];
  }
  for (int i = 0; i < 4; ++i) {
    int bs = g * 4 + i;
    int b = bs >> 11, s = bs & 2047;
    const float4* xp4 = (const float4*)(x + (size_t)bs * 1024 + dm0);
    float4 xa = xp4[0], xbv4 = xp4[1];
    float xv[8] = {xa.x, xa.y, xa.z, xa.w, xbv4.x, xbv4.y, xbv4.z, xbv4.w};
    ushort_t qc[8], qs[8], kc[8], ks[8], xo[8];
#pragma unroll
    for (int j = 0; j < 8; ++j) {
      int iq = ((int)rintf(fmaf(xv[j], aq[j], cq[j]))) & 4095;
      float sq, cqv;
      __sincosf((float)iq * ANG, &sq, &cqv);
      int ik = ((int)rintf(fmaf(xv[j], ak[j], ck[j]))) & 4095;
      float sk, ckv;
      __sincosf((float)ik * ANG, &sk, &ckv);
      qc[j] = f2bf(cqv * QSCL);
      qs[j] = f2bf(sq * QSCL);
      kc[j] = f2bf(ckv);
      ks[j] = f2bf(sk);
      xo[j] = f2bf(xv[j]);
    }
    size_t qb = ((size_t)(b * 16 + h) * 2048 + s) * 128 + (dm0 & 63);
    store8(Qs + qb, qc);        store8(Qs + qb + 64, qs);
    store8(Ks + qb, kc);        store8(Ks + qb + 64, ks);
    store8(xb + (size_t)bs * 1024 + dm0, xo);
  }
}

// ---------------------------------------------------------------- GEMM ------
// Tile 64(m) x 128(n), 4 waves, K-step 64, 512 blocks = 2/CU.
// TRIPLE-buffer single-barrier pipeline (same WAR argument as attn):
// stage(t+2) -> buf[(t+2)%3], last read at t-1, drained before t-1's barrier.
template <int EPI>
__global__ __launch_bounds__(256) void gemm_nt(
    const ushort_t* __restrict__ A, const ushort_t* __restrict__ B,
    float* __restrict__ Cf, ushort_t* __restrict__ Cb, int M, int N, int K)
{
  __shared__ __align__(16) ushort_t As[3][64 * 64];    // 3 x 8KB
  __shared__ __align__(16) ushort_t Bs[3][128 * 64];   // 3 x 16KB (72KB total)
  const int l = threadIdx.x & 63;
  const int w = threadIdx.x >> 6;
  const int g = l >> 4, lo = l & 15;
  const int mt = blockIdx.x % (M >> 6);
  const int nt = blockIdx.x / (M >> 6);
  const int m0 = mt << 6, n0 = nt << 7;

  const f32x4 zero4 = {0.f, 0.f, 0.f, 0.f};
  f32x4 acc[4][2];
#pragma unroll
  for (int i = 0; i < 4; ++i)
#pragma unroll
    for (int j = 0; j < 2; ++j) acc[i][j] = zero4;

  const int nk = K >> 6;   // 16 for K=1024

#define GEMM_STAGE(buf, k0_)                                                    \
  {                                                                             \
    int k0__ = (k0_);                                                           \
    _Pragma("unroll")                                                           \
    for (int i = 0; i < 2; ++i) {                                               \
      int ci = (w * 2 + i) * 64 + l;                                            \
      int r = ci >> 3, c = (ci & 7) ^ (r & 7);                                  \
      gl_lds16(A + (size_t)(m0 + r) * K + k0__ + c * 8, &As[buf][(w * 2 + i) * 512]); \
    }                                                                           \
    _Pragma("unroll")                                                           \
    for (int i = 0; i < 4; ++i) {                                               \
      int ci = (w * 4 + i) * 64 + l;                                            \
      int r = ci >> 3, c = (ci & 7) ^ (r & 7);                                  \
      gl_lds16(B + (size_t)(n0 + r) * K + k0__ + c * 8, &Bs[buf][(w * 4 + i) * 512]); \
    }                                                                           \
  }

  GEMM_STAGE(0, 0);
  GEMM_STAGE(1, 64);
  asm volatile("s_waitcnt vmcnt(6)" ::: "memory");   // tile 0 landed
  __builtin_amdgcn_s_barrier();
  __builtin_amdgcn_sched_barrier(0);

  int rb = 0, wb = 2;
  for (int t = 0; t < nk; ++t) {
#pragma unroll
    for (int kk = 0; kk < 2; ++kk) {
      bf16x8 af[4], bfr[2];
#pragma unroll
      for (int mi = 0; mi < 4; ++mi) {
        int r = mi * 16 + lo;
        int ch = (g + 4 * kk) ^ (r & 7);
        af[mi] = *(const bf16x8*)&As[rb][r * 64 + ch * 8];
      }
#pragma unroll
      for (int ni = 0; ni < 2; ++ni) {
        int r = w * 32 + ni * 16 + lo;
        int ch = (g + 4 * kk) ^ (r & 7);
        bfr[ni] = *(const bf16x8*)&Bs[rb][r * 64 + ch * 8];
      }
#pragma unroll
      for (int mi = 0; mi < 4; ++mi)
#pragma unroll
        for (int ni = 0; ni < 2; ++ni)
          acc[mi][ni] = __builtin_amdgcn_mfma_f32_16x16x32_bf16(af[mi], bfr[ni], acc[mi][ni], 0, 0, 0);
    }
    __builtin_amdgcn_sched_barrier(0);
    if (t + 2 < nk) {
      GEMM_STAGE(wb, (t + 2) * 64);          // buffer last read at t-1: WAR-safe
      asm volatile("s_waitcnt lgkmcnt(0)" ::: "memory");  // own reads of rb done
      asm volatile("s_waitcnt vmcnt(6)" ::: "memory");    // stage(t+1) landed
    } else if (t + 1 < nk) {
      asm volatile("s_waitcnt lgkmcnt(0)" ::: "memory");
      asm volatile("s_waitcnt vmcnt(0)" ::: "memory");
    }
    if (t + 1 < nk) {
      __builtin_amdgcn_s_barrier();          // publish stage(t+1) completion
      __builtin_amdgcn_sched_barrier(0);
    }
    rb = (rb == 2) ? 0 : rb + 1;
    wb = (wb == 2) ? 0 : wb + 1;
  }
#undef GEMM_STAGE

#pragma unroll
  for (int mi = 0; mi < 4; ++mi)
#pragma unroll
    for (int ni = 0; ni < 2; ++ni)
#pragma unroll
      for (int reg = 0; reg < 4; ++reg) {
        int row = m0 + mi * 16 + g * 4 + reg;
        int col = n0 + w * 32 + ni * 16 + lo;
        float v = acc[mi][ni][reg];
        if (EPI == 0) {
          Cf[(size_t)row * N + col] = v;
        } else {
          size_t o = (size_t)(col >> 11) * (1024 * 2048) + (size_t)row * 2048 + (col & 2047);
          Cb[o] = f2bf(v);
        }
      }
}

// ------------------------------------------------------------- attention ----
// Round-14 (best): 512 blocks x 256 threads, 4 waves x 32 q-rows, QBLK=128,
// KVBLK=64, balanced qt pairing, setprio, TRIPLE-buffer + ONE barrier/step.

template<bool MASKED>
__device__ __forceinline__ void attn_tile(
    const ushort_t* __restrict__ Kc, const ushort_t* __restrict__ Vc,
    const bf16x8 (&qf)[2][4], f32x4 (&accO)[2][4], f32x4 (&acc_l)[2],
    int kb, int qw, int lo, int g, const bf16x8& ones)
{
  const f32x4 zero4 = {0.f, 0.f, 0.f, 0.f};
  f32x4 sc[2][4];
#pragma unroll
  for (int qm = 0; qm < 2; ++qm)
#pragma unroll
    for (int ns = 0; ns < 4; ++ns) sc[qm][ns] = zero4;

  // S^T tile: lane holds S[q=qw+qm*16+lo][k=kb+ns*16+g*4+reg]
#pragma unroll
  for (int e = 0; e < 4; ++e) {
#pragma unroll
    for (int ns = 0; ns < 4; ++ns) {
      int kr = ns * 16 + lo;
      int cc = (g + 4 * e) ^ (kr & 7);
      bf16x8 kf = *(const bf16x8*)&Kc[kr * 128 + cc * 8];
#pragma unroll
      for (int qm = 0; qm < 2; ++qm)
        sc[qm][ns] = __builtin_amdgcn_mfma_f32_16x16x32_bf16(kf, qf[qm][e], sc[qm][ns], 0, 0, 0);
    }
  }

  // p = exp2(s), pack to PV A-fragments (registers only)
  bf16x8 pa[2][2];
#pragma unroll
  for (int qm = 0; qm < 2; ++qm) {
#pragma unroll
    for (int ns = 0; ns < 4; ++ns) {
#pragma unroll
      for (int reg = 0; reg < 4; ++reg) {
        float sv = sc[qm][ns][reg];
        if (MASKED) {
          int ka = kb + ns * 16 + g * 4 + reg;
          int qa = qw + qm * 16 + lo;
          sv = (ka <= qa) ? sv : -__builtin_inff();
        }
        pa[qm][ns >> 1][(ns & 1) * 4 + reg] = (__bf16)fast_exp2(sv);
      }
    }
  }

  // O += P V ; rowsum += P * ones
#pragma unroll
  for (int kk = 0; kk < 2; ++kk) {
#pragma unroll
    for (int nd = 0; nd < 4; ++nd) {
      int vr = nd * 16 + lo;
      int h8 = (g & 1) * 4;
      int cc0 = (4 * kk + (g >> 1)) ^ (vr & 7);
      int cc1 = (4 * kk + 2 + (g >> 1)) ^ (vr & 7);
      union { bf16x8 v8; bf16x4 v4[2]; } u;
      u.v4[0] = *(const bf16x4*)&Vc[vr * 64 + cc0 * 8 + h8];
      u.v4[1] = *(const bf16x4*)&Vc[vr * 64 + cc1 * 8 + h8];
#pragma unroll
      for (int qm = 0; qm < 2; ++qm)
        accO[qm][nd] = __builtin_amdgcn_mfma_f32_16x16x32_bf16(pa[qm][kk], u.v8, accO[qm][nd], 0, 0, 0);
    }
#pragma unroll
    for (int qm = 0; qm < 2; ++qm)
      acc_l[qm] = __builtin_amdgcn_mfma_f32_16x16x32_bf16(pa[qm][kk], ones, acc_l[qm], 0, 0, 0);
  }
}

__global__ __launch_bounds__(256) void attn_kernel(
    const ushort_t* __restrict__ Qs, const ushort_t* __restrict__ Ks,
    const ushort_t* __restrict__ Vt, ushort_t* __restrict__ Ob)
{
  const int S = 2048;
  const int id = blockIdx.x;                 // 0..511
  const int bh = id & 31;
  const int qt = (id < 256) ? (15 - (id >> 5)) : ((id - 256) >> 5);
  const int l = threadIdx.x & 63;
  const int w = threadIdx.x >> 6;
  const int g = l >> 4, lo = l & 15;

  __shared__ __align__(16) ushort_t Kl[3][64 * 128];  // 3 x 16KB
  __shared__ __align__(16) ushort_t Vl[3][64 * 64];   // 3 x 8KB  (72KB total)

  const int q0b = qt * 128;
  const int qw = q0b + w * 32;
  const ushort_t* Kbase = Ks + (size_t)bh * S * 128;
  const ushort_t* Vbase = Vt + (size_t)bh * 64 * S;

  bf16x8 ones;
#pragma unroll
  for (int j = 0; j < 8; ++j) ones[j] = (__bf16)1.0f;

  // Q fragments: qf[qm][e] = Q[qw+qm*16+lo][32e+8g .. +7]
  bf16x8 qf[2][4];
#pragma unroll
  for (int qm = 0; qm < 2; ++qm) {
    const ushort_t* qp = Qs + ((size_t)bh * S + qw + qm * 16 + lo) * 128 + 8 * g;
#pragma unroll
    for (int e = 0; e < 4; ++e) qf[qm][e] = *(const bf16x8*)(qp + 32 * e);
  }

  const f32x4 zero4 = {0.f, 0.f, 0.f, 0.f};
  f32x4 accO[2][4];
  f32x4 acc_l[2];
#pragma unroll
  for (int qm = 0; qm < 2; ++qm) {
    acc_l[qm] = zero4;
#pragma unroll
    for (int nd = 0; nd < 4; ++nd) accO[qm][nd] = zero4;
  }

  const int nt = 2 * qt + 2;   // >= 2 always

#define ATTN_STAGE(buf, kb_)                                                    \
  {                                                                             \
    int kb__ = (kb_);                                                           \
    _Pragma("unroll")                                                           \
    for (int i = 0; i < 4; ++i) {                                               \
      int ci = (w * 4 + i) * 64 + l;                                            \
      int r = ci >> 4, c = (ci & 15) ^ (r & 7);                                 \
      gl_lds16(Kbase + (size_t)(kb__ + r) * 128 + c * 8, &Kl[buf][(w * 4 + i) * 512]); \
    }                                                                           \
    _Pragma("unroll")                                                           \
    for (int i = 0; i < 2; ++i) {                                               \
      int ci = (w * 2 + i) * 64 + l;                                            \
      int r = ci >> 3, c = (ci & 7) ^ (r & 7);                                  \
      gl_lds16(Vbase + (size_t)r * S + kb__ + c * 8, &Vl[buf][(w * 2 + i) * 512]); \
    }                                                                           \
  }

  // prologue: stage tiles 0,1 into buf 0,1; confirm tile 0 (6 newest in flight)
  ATTN_STAGE(0, 0);
  ATTN_STAGE(1, 64);
  asm volatile("s_waitcnt vmcnt(6)" ::: "memory");
  __builtin_amdgcn_s_barrier();
  __builtin_amdgcn_sched_barrier(0);

  int rb = 0;                     // t % 3
  int wb = 2;                     // (t+2) % 3
  for (int t = 0; t < nt; ++t) {
    __builtin_amdgcn_s_setprio(1);
    if (t < 2 * qt)
      attn_tile<false>(Kl[rb], Vl[rb], qf, accO, acc_l, t * 64, qw, lo, g, ones);
    else
      attn_tile<true>(Kl[rb], Vl[rb], qf, accO, acc_l, t * 64, qw, lo, g, ones);
    __builtin_amdgcn_s_setprio(0);
    __builtin_amdgcn_sched_barrier(0);
    if (t + 2 < nt) {
      ATTN_STAGE(wb, (t + 2) * 64);          // buffer last read at t-1: WAR-safe
      asm volatile("s_waitcnt lgkmcnt(0)" ::: "memory");  // own reads of rb done
      asm volatile("s_waitcnt vmcnt(6)" ::: "memory");    // own stage(t+1) landed
    } else if (t + 1 < nt) {
      asm volatile("s_waitcnt lgkmcnt(0)" ::: "memory");
      asm volatile("s_waitcnt vmcnt(0)" ::: "memory");    // tail: drain rest
    }
    if (t + 1 < nt) {
      __builtin_amdgcn_s_barrier();          // publish stage(t+1) completion
      __builtin_amdgcn_sched_barrier(0);
    }
    rb = (rb == 2) ? 0 : rb + 1;
    wb = (wb == 2) ? 0 : wb + 1;
  }
#undef ATTN_STAGE

  // normalize: acc_l layout == accO layout (row=(l>>4)*4+reg, replicated cols)
  float linv[2][4];
#pragma unroll
  for (int qm = 0; qm < 2; ++qm)
#pragma unroll
    for (int reg = 0; reg < 4; ++reg)
      linv[qm][reg] = 1.0f / acc_l[qm][reg];

  const int b = bh >> 4, h = bh & 15;
#pragma unroll
  for (int qm = 0; qm < 2; ++qm)
#pragma unroll
    for (int nd = 0; nd < 4; ++nd)
#pragma unroll
      for (int reg = 0; reg < 4; ++reg) {
        int q = qw + qm * 16 + g * 4 + reg;
        int d = nd * 16 + lo;
        Ob[((size_t)(b * 2048 + q)) * 1024 + h * 64 + d] = f2bf(accO[qm][nd][reg] * linv[qm][reg]);
      }
}

// ---------------------------------------------------------------- launch ----
extern "C" void kernel_launch(void* const* d_in, const int* in_sizes, int n_in,
                              void* d_out, int out_size, void* d_ws, size_t ws_size,
                              hipStream_t stream) {
  const float* x  = (const float*)d_in[0];
  const float* wq = (const float*)d_in[1];
  const float* bq = (const float*)d_in[2];
  const float* wk = (const float*)d_in[3];
  const float* bk = (const float*)d_in[4];
  const float* vw = (const float*)d_in[5];
  const float* ow = (const float*)d_in[6];
  float* out = (float*)d_out;

  char* ws = (char*)d_ws;
  ushort_t* Qs  = (ushort_t*)(ws);                      // 16 MB  [32][2048][128]
  ushort_t* Ksb = (ushort_t*)(ws + (16u << 20));        // 16 MB  [32][2048][128]
  ushort_t* Vtb = (ushort_t*)(ws + (32u << 20));        //  8 MB  [32][64][2048]
  ushort_t* xbb = (ushort_t*)(ws + (40u << 20));        //  8 MB  [4096][1024]
  ushort_t* Obb = (ushort_t*)(ws + (48u << 20));        //  8 MB  [4096][1024]
  ushort_t* vwb = (ushort_t*)(ws + (56u << 20));        //  2 MB
  ushort_t* owb = (ushort_t*)(ws + (58u << 20));        //  2 MB

  prep_kernel<<<1536, 256, 0, stream>>>(x, wq, bq, wk, bk, Qs, Ksb, xbb,
                                        vw, ow, vwb, owb);
  gemm_nt<1><<<512, 256, 0, stream>>>(vwb, xbb, nullptr, Vtb, 1024, 4096, 1024);
  attn_kernel<<<512, 256, 0, stream>>>(Qs, Ksb, Vtb, Obb);
  gemm_nt<0><<<512, 256, 0, stream>>>(Obb, owb, out, nullptr, 4096, 1024, 1024);
}